// Round 11
// baseline (213.747 us; speedup 1.0000x reference)
//
#include <hip/hip_runtime.h>
#include <hip/hip_bf16.h>
#include <stdint.h>

// Problem: 3x Bahdanau attention (p/c/h heads) -> averaged softmax weights -> weighted sum of sentence.
// S=8192, H2=1024, A=2048, E=768. All inputs fp32; output fp32 [1024].
// R8: gemm 54.6us (gl_lds A+B, depth-2, XCD map); FETCH 22MB, zero time delta => LDS-pipe bound.
// R11: A fragment-major packed, LDS=B only: gemm 47.8us, conflicts EXACTLY the predicted B-only
//     2.85M -> LDS-pipe model validated. But prep +15us (scattered pack writes).
// R12: (a) B also fragment-major -> gemm has ZERO LDS / ZERO barriers / no manual waitcnt:
//         6 coalesced 1KB reg-loads + 8 MFMA per wave-iter, compiler dataflow vmcnt. Budget:
//         737MB XCD-local L2 ~21us + MFMA 9.6us -> predict ~35us.
//     (b) dst-linear pack mapping both phases: writes perfectly coalesced (1KB/wave), reads
//         64B-granular (cache-line exact). Phase1 packs only live rows (~4MB not 16MB).
//     (c) k_stats folded into k_out (R2-proven redundant-stats); 4 -> 3 graph nodes.

namespace {

constexpr int S = 8192;
constexpr int H = 1024;   // H2
constexpr int A = 2048;
constexpr int E = 768;

typedef __bf16 bf16x8 __attribute__((ext_vector_type(8)));
typedef float f32x4 __attribute__((ext_vector_type(4)));

__device__ __forceinline__ bf16x8 cvt8(float4 lo, float4 hi) {
  bf16x8 r;
  r[0] = (__bf16)lo.x; r[1] = (__bf16)lo.y; r[2] = (__bf16)lo.z; r[3] = (__bf16)lo.w;
  r[4] = (__bf16)hi.x; r[5] = (__bf16)hi.y; r[6] = (__bf16)hi.z; r[7] = (__bf16)hi.w;
  return r;
}

// ---------- merged prep ----------
// packA seg layout (1KB = 512 bf16): seg = g*64 + kt*2 + f; elem (quad*16+l16)*8+e =
//   sentence[g*32 + f*16 + l16][kt*32 + quad*8 + e]   (g: 32-row group, kt: k-tile of 32)
// packB seg layout: seg = (head*128 + cg)*32 + kt; elem (quad*16+l16)*8+e =
//   W_sent[kt*32+quad*8+e][cg*16+l16]                 (cg: 16-col group of A-dim)
// [0,4096)      phase 1: pack sentence -> packA, dst-linear (only row-groups < lenp)
// [4096,5632)   phase 2: W_sent [H][A] -> packB frag-major via LDS transpose tile
// [5632,5728)   phase 3: ctxb_q[q][head][a] partial ctx @ W_ctx (+biases in q0)
// [5728,5736)   phase 4: zero e_arr + out
__global__ __launch_bounds__(256)
void k_prep(const float* __restrict__ sentence, __bf16* __restrict__ packA,
            const float* __restrict__ Wp, const float* __restrict__ Wc_s,
            const float* __restrict__ Wh, __bf16* __restrict__ packB,
            const float* __restrict__ ctx_p, const float* __restrict__ ctx_c,
            const float* __restrict__ ctx_h,
            const float* __restrict__ Wcx_p, const float* __restrict__ Wcx_c,
            const float* __restrict__ Wcx_h,
            const float* __restrict__ bs_p, const float* __restrict__ bs_c,
            const float* __restrict__ bs_h,
            const float* __restrict__ bc_p, const float* __restrict__ bc_c,
            const float* __restrict__ bc_h,
            float* __restrict__ ctxb_q, float* __restrict__ e_arr,
            const int* __restrict__ length, float* __restrict__ out, int n_out) {
  __shared__ float tile[64][65];
  int b = blockIdx.x;
  int t = threadIdx.x;

  if (b < 4096) {
    // ---- phase 1: dst-linear A-pack. Block b owns segs [b*4, b*4+4) (all same row-group).
    int len = min(max(length[0], 0), S);
    int lenp = (len + 63) & ~63;          // GEMM touches rows < round_up(len,64)
    if ((b >> 4) * 32 >= lenp) return;    // b>>4 == row-group g of all 4 segs
    int C = b * 256 + t;                  // global 16B chunk id
    int seg = C >> 6;
    int g = seg >> 6, kt = (seg >> 1) & 31, f = seg & 1;
    int slot = C & 63, quad = slot >> 4, l16 = slot & 15;
    const float4* s4 =
        (const float4*)(sentence + (size_t)(g * 32 + f * 16 + l16) * H + kt * 32 + quad * 8);
    // write: consecutive t -> consecutive 16B (1KB/wave contiguous). read: 64B per row chunk.
    *(bf16x8*)(packA + (size_t)seg * 512 + slot * 8) = cvt8(s4[0], s4[1]);
  } else if (b < 5632) {
    // ---- phase 2: W_sent [H][A] fp32 -> packB frag-major bf16 ----
    int r = b - 4096;                 // 512 tiles per head
    int head = r >> 9; r &= 511;
    const float* W = head == 0 ? Wp : (head == 1 ? Wc_s : Wh);
    int a0 = (r & 31) * 64;           // 32 a-tiles
    int k0 = (r >> 5) * 64;           // 16 k-tiles
#pragma unroll
    for (int i = 0; i < 8; ++i) {
      int idx = t + i * 256;
      int rr = idx >> 5;              // k-row 0..63
      int cc = (idx & 31) * 2;        // a-col pairs: float2 loads
      float2 w2 = *(const float2*)&W[(size_t)(k0 + rr) * A + a0 + cc];
      tile[cc][rr] = w2.x;            // tile[a_local][k_local]
      tile[cc + 1][rr] = w2.y;
    }
    __syncthreads();
    // dst-linear frag write: 512 chunks of 8 elems; chunk c -> seg_local c>>6 (cg-major),
    // slot c&63. Write 16B/thread consecutive (1KB/wave); LDS reads ~2-way (free).
#pragma unroll
    for (int i = 0; i < 2; ++i) {
      int c = t + i * 256;
      int segl = c >> 6;              // 0..7
      int cgl = segl >> 1, ktl = segl & 1;
      int slot = c & 63, quad = slot >> 4, l16 = slot & 15;
      int al = cgl * 16 + l16;
      int kl = ktl * 32 + quad * 8;
      bf16x8 o;
#pragma unroll
      for (int e = 0; e < 8; ++e) o[e] = (__bf16)tile[al][kl + e];
      size_t seg = ((size_t)head * 128 + (a0 >> 4) + cgl) * 32 + (k0 >> 5) + ktl;
      *(bf16x8*)(packB + seg * 512 + slot * 8) = o;
    }
  } else if (b < 5728) {
    // ---- phase 3: ctxb quarter-partials, direct store ----
    int r = b - 5632;                 // 96 blocks: 3 heads x {8 a-blocks x 4 e-quarters}
    int head = r >> 5;
    int sub = r & 31;
    int ablk = sub & 7;
    int eq = sub >> 3;                // e-quarter: 192 elements
    const float* ctx = head == 0 ? ctx_p : (head == 1 ? ctx_c : ctx_h);
    const float* Wc  = head == 0 ? Wcx_p : (head == 1 ? Wcx_c : Wcx_h);
    int a = ablk * 256 + t;
    float s = 0.f;
    if (eq == 0) {
      const float* bs = head == 0 ? bs_p : (head == 1 ? bs_c : bs_h);
      const float* bc = head == 0 ? bc_p : (head == 1 ? bc_c : bc_h);
      s = bs[a] + bc[a];
    }
    int e0 = eq * 192;
#pragma unroll 8
    for (int e = e0; e < e0 + 192; ++e) s = fmaf(ctx[e], Wc[(size_t)e * A + a], s);
    ctxb_q[eq * 3 * A + head * A + a] = s;
  } else {
    // ---- phase 4: zero e_arr (6144 float4) + out ----
    int idx = (b - 5728) * 256 + t;
    float4 z = {0.f, 0.f, 0.f, 0.f};
    int total = 6144 + (n_out >> 2);
    for (int i = idx; i < total; i += 2048) {
      if (i < 6144) ((float4*)e_arr)[i] = z;
      else ((float4*)out)[i - 6144] = z;
    }
  }
}

// ---------- GEMM + fused tanh*v epilogue -> e[head][s] ----------
// 64x128 tile, BK=32, 4 waves (32x64 each). ZERO LDS on the K-path: A and B fragments are
// single coalesced 1KB global_load_dwordx4 each from fragment-major packed buffers (L2-hot
// via XCD panel mapping). No barriers, no manual waitcnt: compiler dataflow inserts exact
// counted vmcnt for register loads. Double-slot (x/y) 1-iter-ahead prefetch; ~5 waves/SIMD
// of TLP hides the rest. LDS only for the 64-row e_part reduction.
__global__ __launch_bounds__(256)
void k_gemm_e(const __bf16* __restrict__ packA, const __bf16* __restrict__ packB,
              const float* __restrict__ ctxb_q,
              const float* __restrict__ v_p, const float* __restrict__ v_c,
              const float* __restrict__ v_h,
              const int* __restrict__ length, float* __restrict__ e_out) {
  int bid = blockIdx.x;
  int xcd = bid & 7;
  int j = bid >> 3;                  // [0, 768)
  int mt = j / 6;                    // m OUTER within XCD: 128 m-tiles
  int pl = j - mt * 6;               // 6 panels per XCD
  int panel = xcd * 6 + pl;          // [0, 48)
  int n0 = (panel & 15) * 128;
  int head = panel >> 4;

  int m0 = mt * 64;
  int len = min(max(length[0], 0), S);
  if (m0 >= len) return;          // masked rows can never influence the softmax
  const float* v  = head == 0 ? v_p : (head == 1 ? v_c : v_h);
  float* e_h = e_out + head * S;

  __shared__ float e_part[64];

  int tid = threadIdx.x;
  if (tid < 64) e_part[tid] = 0.f;
  __syncthreads();                   // no loop barriers anymore: order init before epilogue

  int lane = tid & 63;
  int wave = tid >> 6;
  int wm = wave >> 1, wn = wave & 1;       // wave tile: 32 rows x 64 cols
  int quad = lane >> 4, l16 = lane & 15;

  f32x4 acc[2][4];
#pragma unroll
  for (int i = 0; i < 2; ++i)
#pragma unroll
    for (int j2 = 0; j2 < 4; ++j2) acc[i][j2] = (f32x4){0.f, 0.f, 0.f, 0.f};

  // A: group g = m0/32 + wm; frag (kt,f) at elem offset (g*64 + kt*2 + f)*512 + lane*8.
  const __bf16* gA = packA + ((size_t)(m0 >> 5) + wm) * 64 * 512 + (size_t)lane * 8;
  // B: col-group base cg0 = n0/16 + wn*4; frag (jj,kt) at ((head*128+cg0+jj)*32 + kt)*512.
  const __bf16* gB =
      packB + (((size_t)head * 128 + (n0 >> 4) + wn * 4) * 32) * 512 + (size_t)lane * 8;

  bf16x8 xa0, xa1, ya0, ya1;                  // A slots (f0,f1) x2
  bf16x8 xb0, xb1, xb2, xb3, yb0, yb1, yb2, yb3;  // B slots (jj 0..3) x2

#define LOADA(sl, kt)                                   \
  do {                                                  \
    sl##0 = *(const bf16x8*)(gA + ((kt) << 10));        \
    sl##1 = *(const bf16x8*)(gA + ((kt) << 10) + 512);  \
  } while (0)

#define LOADB(sl, kt)                                        \
  do {                                                       \
    sl##0 = *(const bf16x8*)(gB + ((size_t)(kt) << 9));          \
    sl##1 = *(const bf16x8*)(gB + ((size_t)(32 + (kt)) << 9));   \
    sl##2 = *(const bf16x8*)(gB + ((size_t)(64 + (kt)) << 9));   \
    sl##3 = *(const bf16x8*)(gB + ((size_t)(96 + (kt)) << 9));   \
  } while (0)

#define COMPUTE(asl, bsl)                                                                     \
  do {                                                                                        \
    acc[0][0] = __builtin_amdgcn_mfma_f32_16x16x32_bf16(asl##0, bsl##0, acc[0][0], 0, 0, 0);  \
    acc[1][0] = __builtin_amdgcn_mfma_f32_16x16x32_bf16(asl##1, bsl##0, acc[1][0], 0, 0, 0);  \
    acc[0][1] = __builtin_amdgcn_mfma_f32_16x16x32_bf16(asl##0, bsl##1, acc[0][1], 0, 0, 0);  \
    acc[1][1] = __builtin_amdgcn_mfma_f32_16x16x32_bf16(asl##1, bsl##1, acc[1][1], 0, 0, 0);  \
    acc[0][2] = __builtin_amdgcn_mfma_f32_16x16x32_bf16(asl##0, bsl##2, acc[0][2], 0, 0, 0);  \
    acc[1][2] = __builtin_amdgcn_mfma_f32_16x16x32_bf16(asl##1, bsl##2, acc[1][2], 0, 0, 0);  \
    acc[0][3] = __builtin_amdgcn_mfma_f32_16x16x32_bf16(asl##0, bsl##3, acc[0][3], 0, 0, 0);  \
    acc[1][3] = __builtin_amdgcn_mfma_f32_16x16x32_bf16(asl##1, bsl##3, acc[1][3], 0, 0, 0);  \
  } while (0)

  LOADA(xa, 0);
  LOADB(xb, 0);
#pragma unroll 1
  for (int kt = 0; kt < 30; kt += 2) {
    LOADA(ya, kt + 1);
    LOADB(yb, kt + 1);
    COMPUTE(xa, xb);               // compiler waits exactly on xa/xb (counted vmcnt)
    LOADA(xa, kt + 2);
    LOADB(xb, kt + 2);
    COMPUTE(ya, yb);
  }
  LOADA(ya, 31);
  LOADB(yb, 31);
  COMPUTE(xa, xb);                 // kt = 30
  COMPUTE(ya, yb);                 // kt = 31

#undef LOADA
#undef LOADB
#undef COMPUTE

  float vj[4], cbj[4];
#pragma unroll
  for (int j2 = 0; j2 < 4; ++j2) {
    int col = n0 + wn * 64 + j2 * 16 + l16;
    vj[j2] = v[col];
    // sum the 4 e-quarter partials (L2-hot, 98KB table); biases folded into quarter 0
    cbj[j2] = ctxb_q[head * A + col] + ctxb_q[3 * A + head * A + col] +
              ctxb_q[6 * A + head * A + col] + ctxb_q[9 * A + head * A + col];
  }
#pragma unroll
  for (int i = 0; i < 2; ++i) {
#pragma unroll
    for (int r = 0; r < 4; ++r) {
      float p = 0.f;
#pragma unroll
      for (int j2 = 0; j2 < 4; ++j2) {
        float u = acc[i][j2][r] + cbj[j2];
        float ex = __expf(2.f * u);        // tanh = 1 - 2/(e^2x+1); inf-safe at both ends
        float th = 1.f - 2.f / (ex + 1.f);
        p = fmaf(th, vj[j2], p);
      }
      p += __shfl_xor(p, 1);
      p += __shfl_xor(p, 2);
      p += __shfl_xor(p, 4);
      p += __shfl_xor(p, 8);
      if (l16 == 0) atomicAdd(&e_part[wm * 32 + i * 16 + quad * 4 + r], p);
    }
  }
  __syncthreads();
  if (tid < 64) atomicAdd(&e_h[m0 + tid], e_part[tid]);
}

// ---------- out[h] = sum_s w(s) * sentence[s][h]; stats computed per block (R2-proven) ----------
__global__ void k_out(const float* __restrict__ sent, const float* __restrict__ e_arr,
                      const int* __restrict__ length, float* __restrict__ out) {
  int len = min(max(length[0], 0), S);
  int r0 = blockIdx.x * 16;
  if (r0 >= len) return;
  int tid = threadIdx.x;

  __shared__ float red[3][4];
  __shared__ float sstat[6];    // m0,s0,m1,s1,m2,s2
  __shared__ float wrow[16];

  // pass 1: per-head max over s < len
#pragma unroll
  for (int h = 0; h < 3; ++h) {
    const float* e_h = e_arr + h * S;
    float m = -3.4e38f;
    for (int s = tid; s < len; s += 256) m = fmaxf(m, e_h[s]);
#pragma unroll
    for (int o = 32; o >= 1; o >>= 1) m = fmaxf(m, __shfl_xor(m, o));
    if ((tid & 63) == 0) red[h][tid >> 6] = m;
  }
  __syncthreads();
  if (tid < 3) sstat[tid * 2] = fmaxf(fmaxf(red[tid][0], red[tid][1]),
                                      fmaxf(red[tid][2], red[tid][3]));
  __syncthreads();
  // pass 2: per-head sum of exp
#pragma unroll
  for (int h = 0; h < 3; ++h) {
    const float* e_h = e_arr + h * S;
    float mm = sstat[h * 2];
    float ss = 0.f;
    for (int s = tid; s < len; s += 256) ss += __expf(e_h[s] - mm);
#pragma unroll
    for (int o = 32; o >= 1; o >>= 1) ss += __shfl_xor(ss, o);
    if ((tid & 63) == 0) red[h][tid >> 6] = ss;
  }
  __syncthreads();
  if (tid < 3) sstat[tid * 2 + 1] = red[tid][0] + red[tid][1] + red[tid][2] + red[tid][3];
  __syncthreads();

  if (tid < 16 && r0 + tid < len) {
    int r = r0 + tid;
    wrow[tid] = (__expf(e_arr[r] - sstat[0]) / sstat[1] +
                 __expf(e_arr[S + r] - sstat[2]) / sstat[3] +
                 __expf(e_arr[2 * S + r] - sstat[4]) / sstat[5]) * (1.f / 3.f);
  }
  __syncthreads();

  int col = tid * 4;
  int rend = min(r0 + 16, len);
  float4 acc = {0.f, 0.f, 0.f, 0.f};
  for (int r = r0; r < rend; ++r) {
    float w = wrow[r - r0];
    float4 x = *(const float4*)(sent + (size_t)r * H + col);
    acc.x = fmaf(w, x.x, acc.x);
    acc.y = fmaf(w, x.y, acc.y);
    acc.z = fmaf(w, x.z, acc.z);
    acc.w = fmaf(w, x.w, acc.w);
  }
  atomicAdd(&out[col + 0], acc.x);
  atomicAdd(&out[col + 1], acc.y);
  atomicAdd(&out[col + 2], acc.z);
  atomicAdd(&out[col + 3], acc.w);
}

}  // namespace

extern "C" void kernel_launch(void* const* d_in, const int* in_sizes, int n_in,
                              void* d_out, int out_size, void* d_ws, size_t ws_size,
                              hipStream_t stream) {
  const float* sentence = (const float*)d_in[0];
  const int* length     = (const int*)d_in[1];
  const float* ctx_p = (const float*)d_in[2];
  const float* ctx_c = (const float*)d_in[3];
  const float* ctx_h = (const float*)d_in[4];
  const float* W_s[3] = {(const float*)d_in[5],  (const float*)d_in[11], (const float*)d_in[17]};
  const float* b_s[3] = {(const float*)d_in[6],  (const float*)d_in[12], (const float*)d_in[18]};
  const float* W_c[3] = {(const float*)d_in[7],  (const float*)d_in[13], (const float*)d_in[19]};
  const float* b_c[3] = {(const float*)d_in[8],  (const float*)d_in[14], (const float*)d_in[20]};
  const float* v_[3]  = {(const float*)d_in[9],  (const float*)d_in[15], (const float*)d_in[21]};
  float* out = (float*)d_out;

  // workspace layout (bytes)
  char* ws = (char*)d_ws;
  __bf16* packA  = (__bf16*)(ws);               // 8192*1024*2   = 16777216 (fragment-major)
  __bf16* packB  = (__bf16*)(ws + 16777216);    // 3*2048*1024*2 = 12582912 (fragment-major)
  float* ctxb_q  = (float*)(ws + 29360128);     // 4*3*2048*4    = 98304
  float* e_arr   = (float*)(ws + 29458432);     // 3*8192*4      = 98304

  // 3 graph nodes, no memsets, no cross-kernel atomics except e_arr/out (zeroed in prep).
  k_prep<<<5736, 256, 0, stream>>>(sentence, packA,
                                   W_s[0], W_s[1], W_s[2], packB,
                                   ctx_p, ctx_c, ctx_h,
                                   W_c[0], W_c[1], W_c[2],
                                   b_s[0], b_s[1], b_s[2],
                                   b_c[0], b_c[1], b_c[2], ctxb_q, e_arr,
                                   length, out, out_size);
  k_gemm_e<<<6144, 256, 0, stream>>>(packA, packB, ctxb_q,
                                     v_[0], v_[1], v_[2], length, e_arr);
  k_out<<<S / 16, 256, 0, stream>>>(sentence, e_arr, length, out);
}

// Round 12
// 205.914 us; speedup vs baseline: 1.0380x; 1.0380x over previous
//
#include <hip/hip_runtime.h>
#include <hip/hip_bf16.h>
#include <stdint.h>

// Problem: 3x Bahdanau attention (p/c/h heads) -> averaged softmax weights -> weighted sum of sentence.
// S=8192, H2=1024, A=2048, E=768. All inputs fp32; output fp32 [1024].
// R11: A frag-major + LDS-B: gemm 47.8 (6 LDS-ops/8 MFMA). R12: zero-LDS both: 50.5 --
//     conflicts 0 as predicted but per-wave-private B raised traffic 1.5x and VALUBusy to 38%.
//     Cross-round: traffic +-370MB moves time +-3us => bound is per-MFMA issue/latency, and
//     time tracks loads-per-MFMA: R8 1.1 -> 54.6; R11 0.75 -> 47.8; R12 0.75g -> 50.5.
// R13: (a) 64x64 wave tile (128x128 block, 2x2 waves): 8 coalesced 1KB loads -> 16 MFMA
//         (0.5 loads/MFMA), VALU/MFMA halved, L2 traffic -33% (737MB). VGPR ~170, all 720
//         live blocks co-resident.
//     (b) prep phase-1 flipped: coalesced 32B reads / scattered 16B writes (stores don't
//         stall; L2 write-combines) -- R11's +15us prep regression reversed.
// Ledger: total ~= gemm + ~160us (prep+out ~25us kernel + ~135us fixed harness floor).

namespace {

constexpr int S = 8192;
constexpr int H = 1024;   // H2
constexpr int A = 2048;
constexpr int E = 768;

typedef __bf16 bf16x8 __attribute__((ext_vector_type(8)));
typedef float f32x4 __attribute__((ext_vector_type(4)));

__device__ __forceinline__ bf16x8 cvt8(float4 lo, float4 hi) {
  bf16x8 r;
  r[0] = (__bf16)lo.x; r[1] = (__bf16)lo.y; r[2] = (__bf16)lo.z; r[3] = (__bf16)lo.w;
  r[4] = (__bf16)hi.x; r[5] = (__bf16)hi.y; r[6] = (__bf16)hi.z; r[7] = (__bf16)hi.w;
  return r;
}

// ---------- merged prep ----------
// packA seg layout (1KB = 512 bf16): seg = g*64 + kt*2 + f; elem (quad*16+l16)*8+e =
//   sentence[g*32 + f*16 + l16][kt*32 + quad*8 + e]   (g: 32-row group, kt: k-tile of 32)
// packB seg layout: seg = (head*128 + cg)*32 + kt; elem (quad*16+l16)*8+e =
//   W_sent[kt*32+quad*8+e][cg*16+l16]                 (cg: 16-col group of A-dim)
// [0,4096)      phase 1: pack sentence -> packA; COALESCED reads (consecutive t -> consecutive
//               32B of one row), scattered 16B writes. Only rows < round_up(len,128).
// [4096,5632)   phase 2: W_sent [H][A] -> packB frag-major via LDS transpose tile
// [5632,5728)   phase 3: ctxb_q[q][head][a] partial ctx @ W_ctx (+biases in q0)
// [5728,5736)   phase 4: zero e_arr + out
__global__ __launch_bounds__(256)
void k_prep(const float* __restrict__ sentence, __bf16* __restrict__ packA,
            const float* __restrict__ Wp, const float* __restrict__ Wc_s,
            const float* __restrict__ Wh, __bf16* __restrict__ packB,
            const float* __restrict__ ctx_p, const float* __restrict__ ctx_c,
            const float* __restrict__ ctx_h,
            const float* __restrict__ Wcx_p, const float* __restrict__ Wcx_c,
            const float* __restrict__ Wcx_h,
            const float* __restrict__ bs_p, const float* __restrict__ bs_c,
            const float* __restrict__ bs_h,
            const float* __restrict__ bc_p, const float* __restrict__ bc_c,
            const float* __restrict__ bc_h,
            float* __restrict__ ctxb_q, float* __restrict__ e_arr,
            const int* __restrict__ length, float* __restrict__ out, int n_out) {
  __shared__ float tile[64][65];
  int b = blockIdx.x;
  int t = threadIdx.x;

  if (b < 4096) {
    // ---- phase 1: 2 rows per block; thread C = b*256+t handles row C>>7, 32B chunk C&127.
    int len = min(max(length[0], 0), S);
    int lenp = (len + 127) & ~127;        // GEMM m-tiles are 128 rows now
    if (b * 2 >= lenp) return;
    int C = b * 256 + t;
    int row = C >> 7;                     // consecutive t within a row -> coalesced reads
    int k8 = C & 127;                     // 8-elem chunk
    const float4* s4 = (const float4*)(sentence + (size_t)row * H + k8 * 8);
    int g = row >> 5, f = (row >> 4) & 1, l16 = row & 15;
    int kt = k8 >> 2, quad = k8 & 3;
    size_t dst = ((size_t)(g * 64 + kt * 2 + f)) * 512 + (quad * 16 + l16) * 8;
    *(bf16x8*)(packA + dst) = cvt8(s4[0], s4[1]);   // scattered 16B store (non-blocking)
  } else if (b < 5632) {
    // ---- phase 2: W_sent [H][A] fp32 -> packB frag-major bf16 ----
    int r = b - 4096;                 // 512 tiles per head
    int head = r >> 9; r &= 511;
    const float* W = head == 0 ? Wp : (head == 1 ? Wc_s : Wh);
    int a0 = (r & 31) * 64;           // 32 a-tiles
    int k0 = (r >> 5) * 64;           // 16 k-tiles
#pragma unroll
    for (int i = 0; i < 8; ++i) {
      int idx = t + i * 256;
      int rr = idx >> 5;              // k-row 0..63
      int cc = (idx & 31) * 2;        // a-col pairs: float2 loads
      float2 w2 = *(const float2*)&W[(size_t)(k0 + rr) * A + a0 + cc];
      tile[cc][rr] = w2.x;            // tile[a_local][k_local]
      tile[cc + 1][rr] = w2.y;
    }
    __syncthreads();
#pragma unroll
    for (int i = 0; i < 2; ++i) {
      int c = t + i * 256;
      int segl = c >> 6;              // 0..7
      int cgl = segl >> 1, ktl = segl & 1;
      int slot = c & 63, quad = slot >> 4, l16 = slot & 15;
      int al = cgl * 16 + l16;
      int kl = ktl * 32 + quad * 8;
      bf16x8 o;
#pragma unroll
      for (int e = 0; e < 8; ++e) o[e] = (__bf16)tile[al][kl + e];
      size_t seg = ((size_t)head * 128 + (a0 >> 4) + cgl) * 32 + (k0 >> 5) + ktl;
      *(bf16x8*)(packB + seg * 512 + slot * 8) = o;
    }
  } else if (b < 5728) {
    // ---- phase 3: ctxb quarter-partials, direct store ----
    int r = b - 5632;                 // 96 blocks: 3 heads x {8 a-blocks x 4 e-quarters}
    int head = r >> 5;
    int sub = r & 31;
    int ablk = sub & 7;
    int eq = sub >> 3;                // e-quarter: 192 elements
    const float* ctx = head == 0 ? ctx_p : (head == 1 ? ctx_c : ctx_h);
    const float* Wc  = head == 0 ? Wcx_p : (head == 1 ? Wcx_c : Wcx_h);
    int a = ablk * 256 + t;
    float s = 0.f;
    if (eq == 0) {
      const float* bs = head == 0 ? bs_p : (head == 1 ? bs_c : bs_h);
      const float* bc = head == 0 ? bc_p : (head == 1 ? bc_c : bc_h);
      s = bs[a] + bc[a];
    }
    int e0 = eq * 192;
#pragma unroll 8
    for (int e = e0; e < e0 + 192; ++e) s = fmaf(ctx[e], Wc[(size_t)e * A + a], s);
    ctxb_q[eq * 3 * A + head * A + a] = s;
  } else {
    // ---- phase 4: zero e_arr (6144 float4) + out ----
    int idx = (b - 5728) * 256 + t;
    float4 z = {0.f, 0.f, 0.f, 0.f};
    int total = 6144 + (n_out >> 2);
    for (int i = idx; i < total; i += 2048) {
      if (i < 6144) ((float4*)e_arr)[i] = z;
      else ((float4*)out)[i - 6144] = z;
    }
  }
}

// ---------- GEMM + fused tanh*v epilogue -> e[head][s] ----------
// 128x128 block, 2x2 waves of 64x64 (4x4 16x16x32 frags). ZERO LDS on the K-path: per
// wave-iter 8 coalesced 1KB register loads (4 A-frags + 4 B-frags) feed 16 MFMA -- 0.5
// loads/MFMA (R8 1.1, R11/R12 0.75). No barriers, no manual waitcnt (compiler dataflow
// vmcnt). x/y double-slot 1-iter-ahead prefetch. XCD panel map: xcd=bid&7 owns 6 of 48
// (n,head) panels; m outer. LDS only for the 128-row e_part reduction.
__global__ __launch_bounds__(256)
void k_gemm_e(const __bf16* __restrict__ packA, const __bf16* __restrict__ packB,
              const float* __restrict__ ctxb_q,
              const float* __restrict__ v_p, const float* __restrict__ v_c,
              const float* __restrict__ v_h,
              const int* __restrict__ length, float* __restrict__ e_out) {
  int bid = blockIdx.x;
  int xcd = bid & 7;
  int j = bid >> 3;                  // [0, 384)
  int mt = j / 6;                    // m OUTER within XCD: 64 m-tiles of 128
  int pl = j - mt * 6;               // 6 panels per XCD
  int panel = xcd * 6 + pl;          // [0, 48)
  int n0 = (panel & 15) * 128;
  int head = panel >> 4;

  int m0 = mt * 128;
  int len = min(max(length[0], 0), S);
  if (m0 >= len) return;          // masked rows can never influence the softmax
  const float* v  = head == 0 ? v_p : (head == 1 ? v_c : v_h);
  float* e_h = e_out + head * S;

  __shared__ float e_part[128];

  int tid = threadIdx.x;
  if (tid < 128) e_part[tid] = 0.f;
  __syncthreads();                   // order init before epilogue (no loop barriers exist)

  int lane = tid & 63;
  int wave = tid >> 6;
  int wm = wave >> 1, wn = wave & 1;       // wave tile: 64 rows x 64 cols
  int quad = lane >> 4, l16 = lane & 15;

  f32x4 acc[4][4];
#pragma unroll
  for (int i = 0; i < 4; ++i)
#pragma unroll
    for (int j2 = 0; j2 < 4; ++j2) acc[i][j2] = (f32x4){0.f, 0.f, 0.f, 0.f};

  // A: wave rows = m0 + wm*64 .. +64 = groups gbase, gbase+1 (gbase = m0/32 + wm*2).
  // frag i (rows i*16..+16): seg gbase + (i>>1), f = i&1 -> elem ofs ((i>>1)*64 + kt*2 + (i&1))*512.
  const __bf16* gA = packA + ((size_t)(m0 >> 5) + wm * 2) * 64 * 512 + (size_t)lane * 8;
  // B: col-group base cg0 = n0/16 + wn*4; frag jj at ((head*128+cg0+jj)*32 + kt)*512.
  const __bf16* gB =
      packB + (((size_t)head * 128 + (n0 >> 4) + wn * 4) * 32) * 512 + (size_t)lane * 8;

  bf16x8 xa0, xa1, xa2, xa3, ya0, ya1, ya2, ya3;   // A slots (frag 0..3) x2
  bf16x8 xb0, xb1, xb2, xb3, yb0, yb1, yb2, yb3;   // B slots (frag 0..3) x2

#define LOADA(sl, kt)                                                \
  do {                                                               \
    sl##0 = *(const bf16x8*)(gA + ((size_t)((kt)*2 + 0) << 9));      \
    sl##1 = *(const bf16x8*)(gA + ((size_t)((kt)*2 + 1) << 9));      \
    sl##2 = *(const bf16x8*)(gA + ((size_t)(64 + (kt)*2 + 0) << 9)); \
    sl##3 = *(const bf16x8*)(gA + ((size_t)(64 + (kt)*2 + 1) << 9)); \
  } while (0)

#define LOADB(sl, kt)                                            \
  do {                                                           \
    sl##0 = *(const bf16x8*)(gB + ((size_t)(kt) << 9));          \
    sl##1 = *(const bf16x8*)(gB + ((size_t)(32 + (kt)) << 9));   \
    sl##2 = *(const bf16x8*)(gB + ((size_t)(64 + (kt)) << 9));   \
    sl##3 = *(const bf16x8*)(gB + ((size_t)(96 + (kt)) << 9));   \
  } while (0)

  // A frag i covers rows i*16..+16 of the wave tile; i=0,1 are group gbase (f=0/1),
  // i=2,3 group gbase+1. acc[i][j] = rows i*16, cols j*16.
#define COMPUTE(asl, bsl)                                                                     \
  do {                                                                                        \
    _Pragma("unroll")                                                                         \
    for (int jj = 0; jj < 4; ++jj) {                                                          \
      bf16x8 bf_ = jj == 0 ? bsl##0 : (jj == 1 ? bsl##1 : (jj == 2 ? bsl##2 : bsl##3));       \
      acc[0][jj] = __builtin_amdgcn_mfma_f32_16x16x32_bf16(asl##0, bf_, acc[0][jj], 0, 0, 0); \
      acc[1][jj] = __builtin_amdgcn_mfma_f32_16x16x32_bf16(asl##1, bf_, acc[1][jj], 0, 0, 0); \
      acc[2][jj] = __builtin_amdgcn_mfma_f32_16x16x32_bf16(asl##2, bf_, acc[2][jj], 0, 0, 0); \
      acc[3][jj] = __builtin_amdgcn_mfma_f32_16x16x32_bf16(asl##3, bf_, acc[3][jj], 0, 0, 0); \
    }                                                                                         \
  } while (0)

  LOADA(xa, 0);
  LOADB(xb, 0);
#pragma unroll 1
  for (int kt = 0; kt < 30; kt += 2) {
    LOADA(ya, kt + 1);
    LOADB(yb, kt + 1);
    COMPUTE(xa, xb);               // compiler waits exactly on xa/xb (counted vmcnt)
    LOADA(xa, kt + 2);
    LOADB(xb, kt + 2);
    COMPUTE(ya, yb);
  }
  LOADA(ya, 31);
  LOADB(yb, 31);
  COMPUTE(xa, xb);                 // kt = 30
  COMPUTE(ya, yb);                 // kt = 31

#undef LOADA
#undef LOADB
#undef COMPUTE

  float vj[4], cbj[4];
#pragma unroll
  for (int j2 = 0; j2 < 4; ++j2) {
    int col = n0 + wn * 64 + j2 * 16 + l16;
    vj[j2] = v[col];
    // sum the 4 e-quarter partials (L2-hot, 98KB table); biases folded into quarter 0
    cbj[j2] = ctxb_q[head * A + col] + ctxb_q[3 * A + head * A + col] +
              ctxb_q[6 * A + head * A + col] + ctxb_q[9 * A + head * A + col];
  }
#pragma unroll
  for (int i = 0; i < 4; ++i) {
#pragma unroll
    for (int r = 0; r < 4; ++r) {
      float p = 0.f;
#pragma unroll
      for (int j2 = 0; j2 < 4; ++j2) {
        float u = acc[i][j2][r] + cbj[j2];
        float ex = __expf(2.f * u);        // tanh = 1 - 2/(e^2x+1); inf-safe at both ends
        float th = 1.f - 2.f / (ex + 1.f);
        p = fmaf(th, vj[j2], p);
      }
      p += __shfl_xor(p, 1);
      p += __shfl_xor(p, 2);
      p += __shfl_xor(p, 4);
      p += __shfl_xor(p, 8);
      if (l16 == 0) atomicAdd(&e_part[wm * 64 + i * 16 + quad * 4 + r], p);
    }
  }
  __syncthreads();
  if (tid < 128) atomicAdd(&e_h[m0 + tid], e_part[tid]);
}

// ---------- out[h] = sum_s w(s) * sentence[s][h]; stats computed per block (R2-proven) ----------
__global__ void k_out(const float* __restrict__ sent, const float* __restrict__ e_arr,
                      const int* __restrict__ length, float* __restrict__ out) {
  int len = min(max(length[0], 0), S);
  int r0 = blockIdx.x * 16;
  if (r0 >= len) return;
  int tid = threadIdx.x;

  __shared__ float red[3][4];
  __shared__ float sstat[6];    // m0,s0,m1,s1,m2,s2
  __shared__ float wrow[16];

  // pass 1: per-head max over s < len
#pragma unroll
  for (int h = 0; h < 3; ++h) {
    const float* e_h = e_arr + h * S;
    float m = -3.4e38f;
    for (int s = tid; s < len; s += 256) m = fmaxf(m, e_h[s]);
#pragma unroll
    for (int o = 32; o >= 1; o >>= 1) m = fmaxf(m, __shfl_xor(m, o));
    if ((tid & 63) == 0) red[h][tid >> 6] = m;
  }
  __syncthreads();
  if (tid < 3) sstat[tid * 2] = fmaxf(fmaxf(red[tid][0], red[tid][1]),
                                      fmaxf(red[tid][2], red[tid][3]));
  __syncthreads();
  // pass 2: per-head sum of exp
#pragma unroll
  for (int h = 0; h < 3; ++h) {
    const float* e_h = e_arr + h * S;
    float mm = sstat[h * 2];
    float ss = 0.f;
    for (int s = tid; s < len; s += 256) ss += __expf(e_h[s] - mm);
#pragma unroll
    for (int o = 32; o >= 1; o >>= 1) ss += __shfl_xor(ss, o);
    if ((tid & 63) == 0) red[h][tid >> 6] = ss;
  }
  __syncthreads();
  if (tid < 3) sstat[tid * 2 + 1] = red[tid][0] + red[tid][1] + red[tid][2] + red[tid][3];
  __syncthreads();

  if (tid < 16 && r0 + tid < len) {
    int r = r0 + tid;
    wrow[tid] = (__expf(e_arr[r] - sstat[0]) / sstat[1] +
                 __expf(e_arr[S + r] - sstat[2]) / sstat[3] +
                 __expf(e_arr[2 * S + r] - sstat[4]) / sstat[5]) * (1.f / 3.f);
  }
  __syncthreads();

  int col = tid * 4;
  int rend = min(r0 + 16, len);
  float4 acc = {0.f, 0.f, 0.f, 0.f};
  for (int r = r0; r < rend; ++r) {
    float w = wrow[r - r0];
    float4 x = *(const float4*)(sent + (size_t)r * H + col);
    acc.x = fmaf(w, x.x, acc.x);
    acc.y = fmaf(w, x.y, acc.y);
    acc.z = fmaf(w, x.z, acc.z);
    acc.w = fmaf(w, x.w, acc.w);
  }
  atomicAdd(&out[col + 0], acc.x);
  atomicAdd(&out[col + 1], acc.y);
  atomicAdd(&out[col + 2], acc.z);
  atomicAdd(&out[col + 3], acc.w);
}

}  // namespace

extern "C" void kernel_launch(void* const* d_in, const int* in_sizes, int n_in,
                              void* d_out, int out_size, void* d_ws, size_t ws_size,
                              hipStream_t stream) {
  const float* sentence = (const float*)d_in[0];
  const int* length     = (const int*)d_in[1];
  const float* ctx_p = (const float*)d_in[2];
  const float* ctx_c = (const float*)d_in[3];
  const float* ctx_h = (const float*)d_in[4];
  const float* W_s[3] = {(const float*)d_in[5],  (const float*)d_in[11], (const float*)d_in[17]};
  const float* b_s[3] = {(const float*)d_in[6],  (const float*)d_in[12], (const float*)d_in[18]};
  const float* W_c[3] = {(const float*)d_in[7],  (const float*)d_in[13], (const float*)d_in[19]};
  const float* b_c[3] = {(const float*)d_in[8],  (const float*)d_in[14], (const float*)d_in[20]};
  const float* v_[3]  = {(const float*)d_in[9],  (const float*)d_in[15], (const float*)d_in[21]};
  float* out = (float*)d_out;

  // workspace layout (bytes)
  char* ws = (char*)d_ws;
  __bf16* packA  = (__bf16*)(ws);               // 8192*1024*2   = 16777216 (fragment-major)
  __bf16* packB  = (__bf16*)(ws + 16777216);    // 3*2048*1024*2 = 12582912 (fragment-major)
  float* ctxb_q  = (float*)(ws + 29360128);     // 4*3*2048*4    = 98304
  float* e_arr   = (float*)(ws + 29458432);     // 3*8192*4      = 98304

  // 3 graph nodes, no memsets, no cross-kernel atomics except e_arr/out (zeroed in prep).
  k_prep<<<5736, 256, 0, stream>>>(sentence, packA,
                                   W_s[0], W_s[1], W_s[2], packB,
                                   ctx_p, ctx_c, ctx_h,
                                   W_c[0], W_c[1], W_c[2],
                                   b_s[0], b_s[1], b_s[2],
                                   b_c[0], b_c[1], b_c[2], ctxb_q, e_arr,
                                   length, out, out_size);
  k_gemm_e<<<3072, 256, 0, stream>>>(packA, packB, ctxb_q,
                                     v_[0], v_[1], v_[2], length, e_arr);
  k_out<<<S / 16, 256, 0, stream>>>(sentence, e_arr, length, out);
}